// Round 8
// baseline (171.013 us; speedup 1.0000x reference)
//
#include <hip/hip_runtime.h>

#define IMG  1024
#define TS   32
#define XTW  40            // xt cols: img C0-4 .. C0+35 (16B-aligned f4 halo)
#define XTH  38            // xt rows: img R0-3 .. R0+34
#define XTA  (XTH*XTW)
#define NSEG (3*XTH*10)    // 1140 f4 halo segments
#define SG   36            // s1/a2/a3 grid: img (R0-2+r, C0-2+c), r,c in 0..35
#define S2G  34            // s2 grid:      img (R0-1+r, C0-1+c), r,c in 0..33
#define OUT1 (2*IMG*IMG)
#define OUT2 (OUT1 + 6*IMG*IMG)

__device__ __forceinline__ float sigf(float y) { return 1.0f / (1.0f + __expf(-y)); }

__global__ __launch_bounds__(256, 4)
void unet_fused(const float* __restrict__ x, const float* __restrict__ x2,
                const float* __restrict__ w1a, const float* __restrict__ b1a,
                const float* __restrict__ w2a, const float* __restrict__ b2a,
                const float* __restrict__ w3a, const float* __restrict__ b3a,
                const float* __restrict__ w1b, const float* __restrict__ b1b,
                const float* __restrict__ w2b, const float* __restrict__ b2b,
                const float* __restrict__ w3b, const float* __restrict__ b3b,
                const float* __restrict__ lw1, const float* __restrict__ lb1,
                const float* __restrict__ lw2, const float* __restrict__ lb2,
                float* __restrict__ out)
{
    __shared__ float xt[3][XTA];     // 18240 B
    __shared__ float s1[SG * SG];    //  5184 B  sig(conv1)
    __shared__ float a2b[SG * SG];   //  5184 B  b2 + conv2 x-part
    __shared__ float a3b[SG * SG];   //  5184 B  b3 + conv3 x-part
    __shared__ float s2[S2G * S2G];  //  4624 B  sig(conv2)
    __shared__ float wc[14];         // collapsed 6->2 affine      total ~38.4 KB

    const int tid = threadIdx.x;

    // NO swizzle (A/B vs R6: isolate swizzle <-> WRITE_SIZE amplification)
    const int bx = blockIdx.x, by = blockIdx.y;
    const int R0 = by * TS, C0 = bx * TS;
    const bool edge = (bx == 0) | (bx == 31) | (by == 0) | (by == 31);

    // collapsed linear map (before first barrier)
    if (tid < 12) {
        int o = tid / 6, ch = tid - o * 6;
        float acc = 0.0f;
        for (int k = 0; k < 128; ++k) acc += lw2[o * 128 + k] * lw1[k * 6 + ch];
        wc[tid] = acc;
    } else if (tid < 14) {
        int o = tid - 12;
        float acc = lb2[o];
        for (int k = 0; k < 128; ++k) acc += lw2[o * 128 + k] * lb1[k];
        wc[tid] = acc;
    }

    const float* XS[2] = {x, x2};
    const float* W1[2] = {w1a, w1b};
    const float* W2[2] = {w2a, w2b};
    const float* W3[2] = {w3a, w3b};
    const float* B1[2] = {b1a, b1b};
    const float* B2[2] = {b2a, b2b};
    const float* B3[2] = {b3a, b3b};

    // ---- register prefetch of BOTH branches' halos (interior blocks) ----
    // 1140 f4 segments -> k<5 per thread (FIX of R7's it<660 bug).
    float4 h[2][5];
    int hoff[5];
    if (!edge) {
#pragma unroll
        for (int k = 0; k < 5; ++k) {
            int it = tid + k * 256;
            if (it < NSEG) {
                int ch = it / (XTH * 10); int rem = it - ch * (XTH * 10);
                int row = rem / 10, seg = rem - row * 10;
                int g = ch * (IMG * IMG) + (R0 - 3 + row) * IMG + (C0 - 4) + seg * 4;
                h[0][k] = *(const float4*)(x  + g);
                h[1][k] = *(const float4*)(x2 + g);
                hoff[k] = ch * XTA + row * XTW + seg * 4;
            }
        }
    }

    float pa[4][2];                  // branch-a projected outfeature terms

#pragma unroll
    for (int br = 0; br < 2; ++br) {
        __syncthreads();             // previous branch done reading xt
        // ---------------- halo into LDS ----------------
        if (!edge) {
#pragma unroll
            for (int k = 0; k < 5; ++k) {
                int it = tid + k * 256;
                if (it < NSEG)
                    *(float4*)(&xt[0][hoff[k]]) = h[br][k];
            }
        } else {
            const float* xin = XS[br];
            for (int it = tid; it < 3 * XTA; it += 256) {
                int ch = it / XTA; int rem = it - ch * XTA;
                int row = rem / XTW, col = rem - row * XTW;
                int gr = R0 - 3 + row, gc = C0 - 4 + col;
                float v = 0.0f;
                if ((unsigned)gr < (unsigned)IMG && (unsigned)gc < (unsigned)IMG)
                    v = xin[ch * (IMG * IMG) + gr * IMG + gc];
                xt[ch][rem] = v;
            }
        }
        __syncthreads();

        const float b1v = B1[br][0], b2v = B2[br][0], b3v = B3[br][0];

        // ---- pass A: fused x-sweep -> s1, a2 (=b2+conv2_x), a3 (=b3+conv3_x) on 36x36 grid ----
        if (tid < 216) {                                  // 36 cols x 6 strips of 6 rows (exact)
            int strip = tid / 36, sc = tid - strip * 36;
            int r0 = strip * 6;
            float acc1[6], acc2[6], acc3[6];
#pragma unroll
            for (int q = 0; q < 6; ++q) { acc1[q] = b1v; acc2[q] = b2v; acc3[q] = b3v; }
            for (int ch = 0; ch < 3; ++ch) {
                float u9[9], v9[9], w9[9];
#pragma unroll
                for (int i = 0; i < 9; ++i) {
                    u9[i] = W1[br][ch * 9 + i];
                    v9[i] = W2[br][ch * 9 + i];
                    w9[i] = W3[br][ch * 9 + i];
                }
                const float* xp = &xt[ch][r0 * XTW + sc + 1];   // window cols sc+1..sc+3
#pragma unroll
                for (int rr = 0; rr < 8; ++rr) {                 // xt rows r0..r0+7
                    float a0 = xp[0], a1 = xp[1], a2v = xp[2];
                    xp += XTW;
#pragma unroll
                    for (int dy = 0; dy < 3; ++dy) {
                        int q = rr - dy;
                        if (q >= 0 && q < 6) {
                            acc1[q] += u9[dy * 3] * a0 + u9[dy * 3 + 1] * a1 + u9[dy * 3 + 2] * a2v;
                            acc2[q] += v9[dy * 3] * a0 + v9[dy * 3 + 1] * a1 + v9[dy * 3 + 2] * a2v;
                            acc3[q] += w9[dy * 3] * a0 + w9[dy * 3 + 1] * a1 + w9[dy * 3 + 2] * a2v;
                        }
                    }
                }
            }
            int gcol = C0 - 2 + sc;
            bool cok = (unsigned)gcol < (unsigned)IMG;
            int grow0 = R0 - 2 + r0;
#pragma unroll
            for (int q = 0; q < 6; ++q) {
                bool ok = cok && ((unsigned)(grow0 + q) < (unsigned)IMG);
                int o = (r0 + q) * SG + sc;
                s1[o]  = ok ? sigf(acc1[q]) : 0.0f;
                a2b[o] = acc2[q];
                a3b[o] = acc3[q];
            }
        }
        __syncthreads();

        // ---- pass B: s2 = sig(a2 + conv(s1)) on 34x34 grid ----
        if (tid < 204) {                                  // 34 cols x 6 strips (last strip 4 rows)
            int strip = tid / 34, sc = tid - strip * 34;
            int r0 = strip * 6;
            float acc[6];
#pragma unroll
            for (int q = 0; q < 6; ++q) {
                int ar = r0 + q + 1; if (ar > 35) ar = 35;       // tail clamp (q>=nq unused)
                acc[q] = a2b[ar * SG + sc + 1];
            }
            float w9[9];
#pragma unroll
            for (int i = 0; i < 9; ++i) w9[i] = W2[br][27 + i];
#pragma unroll
            for (int rr = 0; rr < 8; ++rr) {                     // s1 rows r0..r0+7 (clamped)
                int srow = r0 + rr; if (srow > 35) srow = 35;
                const float* p = &s1[srow * SG + sc];
                float a0 = p[0], a1 = p[1], a2v = p[2];
#pragma unroll
                for (int dy = 0; dy < 3; ++dy) {
                    int q = rr - dy;
                    if (q >= 0 && q < 6)
                        acc[q] += w9[dy * 3] * a0 + w9[dy * 3 + 1] * a1 + w9[dy * 3 + 2] * a2v;
                }
            }
            int gcol = C0 - 1 + sc;
            bool cok = (unsigned)gcol < (unsigned)IMG;
            int grow0 = R0 - 1 + r0;
#pragma unroll
            for (int q = 0; q < 6; ++q) {
                int sr = r0 + q;
                if (sr < S2G) {
                    bool ok = cok && ((unsigned)(grow0 + q) < (unsigned)IMG);
                    s2[sr * S2G + sc] = ok ? sigf(acc[q]) : 0.0f;
                }
            }
        }
        __syncthreads();

        // ---- pass C: out = sig(a3 + conv(s1) + conv(s2)); gather + writes (256 items exact) ----
        {
            const int c = tid & 31, rs = tid >> 5;
            const int r0 = rs * 4;                         // final rows r0..r0+3
            float acc[4], c1[4], c2[4];
#pragma unroll
            for (int q = 0; q < 4; ++q) acc[q] = a3b[(r0 + q + 2) * SG + (c + 2)];
            {
                float w9[9];
#pragma unroll
                for (int i = 0; i < 9; ++i) w9[i] = W3[br][27 + i];
                const float* p = &s1[(r0 + 1) * SG + (c + 1)];
#pragma unroll
                for (int rr = 0; rr < 6; ++rr) {           // s1 rows r0+1..r0+6
                    float a0 = p[0], a1 = p[1], a2v = p[2];
                    p += SG;
                    if (rr >= 1 && rr <= 4) c1[rr - 1] = a1;   // s1 center (r+2,c+2)
#pragma unroll
                    for (int dy = 0; dy < 3; ++dy) {
                        int q = rr - dy;
                        if (q >= 0 && q < 4)
                            acc[q] += w9[dy * 3] * a0 + w9[dy * 3 + 1] * a1 + w9[dy * 3 + 2] * a2v;
                    }
                }
            }
            {
                float w9[9];
#pragma unroll
                for (int i = 0; i < 9; ++i) w9[i] = W3[br][36 + i];
                const float* p = &s2[r0 * S2G + c];
#pragma unroll
                for (int rr = 0; rr < 6; ++rr) {           // s2 rows r0..r0+5
                    float a0 = p[0], a1 = p[1], a2v = p[2];
                    p += S2G;
                    if (rr >= 1 && rr <= 4) c2[rr - 1] = a1;   // s2 center (r+1,c+1)
#pragma unroll
                    for (int dy = 0; dy < 3; ++dy) {
                        int q = rr - dy;
                        if (q >= 0 && q < 4)
                            acc[q] += w9[dy * 3] * a0 + w9[dy * 3 + 1] * a1 + w9[dy * 3 + 2] * a2v;
                    }
                }
            }

            const int denOff = (br == 0) ? OUT1 : OUT2;
#pragma unroll
            for (int q = 0; q < 4; ++q) {
                float cur[6];
#pragma unroll
                for (int ch = 0; ch < 3; ++ch)
                    cur[ch] = xt[ch][(r0 + q + 3) * XTW + (c + 4)];
                cur[3] = c1[q];
                cur[4] = c2[q];
                cur[5] = sigf(acc[q]);

                int pix = (R0 + r0 + q) * IMG + C0 + c;
                float* pd = out + denOff + pix * 6;        // R2-proven write pattern (frozen)
#pragma unroll
                for (int ch = 0; ch < 6; ++ch) pd[ch] = cur[ch];

                if (br == 0) {
                    float p0 = 0.0f, p1 = 0.0f;
#pragma unroll
                    for (int ch = 0; ch < 6; ++ch) {
                        p0 += wc[ch]     * cur[ch];
                        p1 += wc[6 + ch] * cur[ch];
                    }
                    pa[q][0] = p0; pa[q][1] = p1;
                } else {
                    float o0 = pa[q][0] + wc[12];
                    float o1 = pa[q][1] + wc[13];
#pragma unroll
                    for (int ch = 0; ch < 6; ++ch) {
                        o0 -= wc[ch]     * cur[ch];
                        o1 -= wc[6 + ch] * cur[ch];
                    }
                    *(float2*)(out + pix * 2) = make_float2(o0, o1);
                }
            }
        }
    }
}

extern "C" void kernel_launch(void* const* d_in, const int* in_sizes, int n_in,
                              void* d_out, int out_size, void* d_ws, size_t ws_size,
                              hipStream_t stream) {
    const float* x   = (const float*)d_in[0];
    const float* x2  = (const float*)d_in[1];
    const float* w1a = (const float*)d_in[2];
    const float* b1a = (const float*)d_in[3];
    const float* w2a = (const float*)d_in[4];
    const float* b2a = (const float*)d_in[5];
    const float* w3a = (const float*)d_in[6];
    const float* b3a = (const float*)d_in[7];
    const float* w1b = (const float*)d_in[8];
    const float* b1b = (const float*)d_in[9];
    const float* w2b = (const float*)d_in[10];
    const float* b2b = (const float*)d_in[11];
    const float* w3b = (const float*)d_in[12];
    const float* b3b = (const float*)d_in[13];
    const float* lw1 = (const float*)d_in[14];
    const float* lb1 = (const float*)d_in[15];
    const float* lw2 = (const float*)d_in[16];
    const float* lb2 = (const float*)d_in[17];
    float* out = (float*)d_out;

    dim3 grid(IMG / TS, IMG / TS);   // 32 x 32 = 1024 blocks
    unet_fused<<<grid, 256, 0, stream>>>(x, x2,
                                         w1a, b1a, w2a, b2a, w3a, b3a,
                                         w1b, b1b, w2b, b2b, w3b, b3b,
                                         lw1, lb1, lw2, lb2, out);
}

// Round 9
// 163.067 us; speedup vs baseline: 1.0487x; 1.0487x over previous
//
#include <hip/hip_runtime.h>

#define IMG  1024
#define TS   32
#define XTW  40            // xt cols: img C0-4 .. C0+35
#define XTH  38            // xt rows: img R0-3 .. R0+34
#define XTA  (XTH*XTW)
#define SG   36            // s1/a2/a3 grid: img (R0-2+r, C0-2+c), r,c in 0..35
#define S2G  34            // s2 grid:      img (R0-1+r, C0-1+c), r,c in 0..33
#define OUT1 (2*IMG*IMG)
#define OUT2 (OUT1 + 6*IMG*IMG)

__device__ __forceinline__ float sigf(float y) { return 1.0f / (1.0f + __expf(-y)); }

__global__ __launch_bounds__(256, 4)
void unet_fused(const float* __restrict__ x, const float* __restrict__ x2,
                const float* __restrict__ w1a, const float* __restrict__ b1a,
                const float* __restrict__ w2a, const float* __restrict__ b2a,
                const float* __restrict__ w3a, const float* __restrict__ b3a,
                const float* __restrict__ w1b, const float* __restrict__ b1b,
                const float* __restrict__ w2b, const float* __restrict__ b2b,
                const float* __restrict__ w3b, const float* __restrict__ b3b,
                const float* __restrict__ lw1, const float* __restrict__ lb1,
                const float* __restrict__ lw2, const float* __restrict__ lb2,
                float* __restrict__ out)
{
    __shared__ float xt[3][XTA];     // 18240 B
    __shared__ float s1[SG * SG];    //  5184 B  sig(conv1)
    __shared__ float a2b[SG * SG];   //  5184 B  b2 + conv2 x-part
    __shared__ float a3b[SG * SG];   //  5184 B  b3 + conv3 x-part
    __shared__ float s2[S2G * S2G];  //  4624 B  sig(conv2)
    __shared__ float wc[14];         // collapsed 6->2 affine      total ~38.4 KB

    const int tid = threadIdx.x;

    // R2-proven memory envelope: plain raster blocks, no swizzle
    const int bx = blockIdx.x, by = blockIdx.y;
    const int R0 = by * TS, C0 = bx * TS;

    // collapsed linear map (before first barrier)
    if (tid < 12) {
        int o = tid / 6, ch = tid - o * 6;
        float acc = 0.0f;
        for (int k = 0; k < 128; ++k) acc += lw2[o * 128 + k] * lw1[k * 6 + ch];
        wc[tid] = acc;
    } else if (tid < 14) {
        int o = tid - 12;
        float acc = lb2[o];
        for (int k = 0; k < 128; ++k) acc += lw2[o * 128 + k] * lb1[k];
        wc[tid] = acc;
    }

    const float* XS[2] = {x, x2};
    const float* W1[2] = {w1a, w1b};
    const float* W2[2] = {w2a, w2b};
    const float* W3[2] = {w3a, w3b};
    const float* B1[2] = {b1a, b1b};
    const float* B2[2] = {b2a, b2b};
    const float* B3[2] = {b3a, b3b};

    float pa[4][2];                  // branch-a projected outfeature terms

#pragma unroll
    for (int br = 0; br < 2; ++br) {
        __syncthreads();             // previous branch done reading xt
        // ---------------- halo load: R2-proven scalar bounds-checked loop (all blocks) ----------------
        {
            const float* xin = XS[br];
            for (int it = tid; it < 3 * XTA; it += 256) {
                int ch = it / XTA; int rem = it - ch * XTA;
                int row = rem / XTW, col = rem - row * XTW;
                int gr = R0 - 3 + row, gc = C0 - 4 + col;
                float v = 0.0f;
                if ((unsigned)gr < (unsigned)IMG && (unsigned)gc < (unsigned)IMG)
                    v = xin[ch * (IMG * IMG) + gr * IMG + gc];
                xt[ch][rem] = v;
            }
        }
        __syncthreads();

        const float b1v = B1[br][0], b2v = B2[br][0], b3v = B3[br][0];

        // ---- pass A: fused x-sweep -> s1, a2 (=b2+conv2_x), a3 (=b3+conv3_x) on 36x36 grid ----
        if (tid < 216) {                                  // 36 cols x 6 strips of 6 rows (exact)
            int strip = tid / 36, sc = tid - strip * 36;
            int r0 = strip * 6;
            float acc1[6], acc2[6], acc3[6];
#pragma unroll
            for (int q = 0; q < 6; ++q) { acc1[q] = b1v; acc2[q] = b2v; acc3[q] = b3v; }
            for (int ch = 0; ch < 3; ++ch) {
                float u9[9], v9[9], w9[9];
#pragma unroll
                for (int i = 0; i < 9; ++i) {
                    u9[i] = W1[br][ch * 9 + i];
                    v9[i] = W2[br][ch * 9 + i];
                    w9[i] = W3[br][ch * 9 + i];
                }
                const float* xp = &xt[ch][r0 * XTW + sc + 1];   // window cols sc+1..sc+3
#pragma unroll
                for (int rr = 0; rr < 8; ++rr) {                 // xt rows r0..r0+7
                    float a0 = xp[0], a1 = xp[1], a2v = xp[2];
                    xp += XTW;
#pragma unroll
                    for (int dy = 0; dy < 3; ++dy) {
                        int q = rr - dy;
                        if (q >= 0 && q < 6) {
                            acc1[q] += u9[dy * 3] * a0 + u9[dy * 3 + 1] * a1 + u9[dy * 3 + 2] * a2v;
                            acc2[q] += v9[dy * 3] * a0 + v9[dy * 3 + 1] * a1 + v9[dy * 3 + 2] * a2v;
                            acc3[q] += w9[dy * 3] * a0 + w9[dy * 3 + 1] * a1 + w9[dy * 3 + 2] * a2v;
                        }
                    }
                }
            }
            int gcol = C0 - 2 + sc;
            bool cok = (unsigned)gcol < (unsigned)IMG;
            int grow0 = R0 - 2 + r0;
#pragma unroll
            for (int q = 0; q < 6; ++q) {
                bool ok = cok && ((unsigned)(grow0 + q) < (unsigned)IMG);
                int o = (r0 + q) * SG + sc;
                s1[o]  = ok ? sigf(acc1[q]) : 0.0f;
                a2b[o] = acc2[q];
                a3b[o] = acc3[q];
            }
        }
        __syncthreads();

        // ---- pass B: s2 = sig(a2 + conv(s1)) on 34x34 grid ----
        if (tid < 204) {                                  // 34 cols x 6 strips (last strip 4 rows)
            int strip = tid / 34, sc = tid - strip * 34;
            int r0 = strip * 6;
            float acc[6];
#pragma unroll
            for (int q = 0; q < 6; ++q) {
                int ar = r0 + q + 1; if (ar > 35) ar = 35;       // tail clamp (q>=nq unused)
                acc[q] = a2b[ar * SG + sc + 1];
            }
            float w9[9];
#pragma unroll
            for (int i = 0; i < 9; ++i) w9[i] = W2[br][27 + i];
#pragma unroll
            for (int rr = 0; rr < 8; ++rr) {                     // s1 rows r0..r0+7 (clamped)
                int srow = r0 + rr; if (srow > 35) srow = 35;
                const float* p = &s1[srow * SG + sc];
                float a0 = p[0], a1 = p[1], a2v = p[2];
#pragma unroll
                for (int dy = 0; dy < 3; ++dy) {
                    int q = rr - dy;
                    if (q >= 0 && q < 6)
                        acc[q] += w9[dy * 3] * a0 + w9[dy * 3 + 1] * a1 + w9[dy * 3 + 2] * a2v;
                }
            }
            int gcol = C0 - 1 + sc;
            bool cok = (unsigned)gcol < (unsigned)IMG;
            int grow0 = R0 - 1 + r0;
#pragma unroll
            for (int q = 0; q < 6; ++q) {
                int sr = r0 + q;
                if (sr < S2G) {
                    bool ok = cok && ((unsigned)(grow0 + q) < (unsigned)IMG);
                    s2[sr * S2G + sc] = ok ? sigf(acc[q]) : 0.0f;
                }
            }
        }
        __syncthreads();

        // ---- pass C: out = sig(a3 + conv(s1) + conv(s2)); gather + writes (256 items exact) ----
        {
            const int c = tid & 31, rs = tid >> 5;
            const int r0 = rs * 4;                         // final rows r0..r0+3
            float acc[4], c1[4], c2[4];
#pragma unroll
            for (int q = 0; q < 4; ++q) acc[q] = a3b[(r0 + q + 2) * SG + (c + 2)];
            {
                float w9[9];
#pragma unroll
                for (int i = 0; i < 9; ++i) w9[i] = W3[br][27 + i];
                const float* p = &s1[(r0 + 1) * SG + (c + 1)];
#pragma unroll
                for (int rr = 0; rr < 6; ++rr) {           // s1 rows r0+1..r0+6
                    float a0 = p[0], a1 = p[1], a2v = p[2];
                    p += SG;
                    if (rr >= 1 && rr <= 4) c1[rr - 1] = a1;   // s1 center (r+2,c+2)
#pragma unroll
                    for (int dy = 0; dy < 3; ++dy) {
                        int q = rr - dy;
                        if (q >= 0 && q < 4)
                            acc[q] += w9[dy * 3] * a0 + w9[dy * 3 + 1] * a1 + w9[dy * 3 + 2] * a2v;
                    }
                }
            }
            {
                float w9[9];
#pragma unroll
                for (int i = 0; i < 9; ++i) w9[i] = W3[br][36 + i];
                const float* p = &s2[r0 * S2G + c];
#pragma unroll
                for (int rr = 0; rr < 6; ++rr) {           // s2 rows r0..r0+5
                    float a0 = p[0], a1 = p[1], a2v = p[2];
                    p += S2G;
                    if (rr >= 1 && rr <= 4) c2[rr - 1] = a1;   // s2 center (r+1,c+1)
#pragma unroll
                    for (int dy = 0; dy < 3; ++dy) {
                        int q = rr - dy;
                        if (q >= 0 && q < 4)
                            acc[q] += w9[dy * 3] * a0 + w9[dy * 3 + 1] * a1 + w9[dy * 3 + 2] * a2v;
                    }
                }
            }

            const int denOff = (br == 0) ? OUT1 : OUT2;
#pragma unroll
            for (int q = 0; q < 4; ++q) {
                float cur[6];
#pragma unroll
                for (int ch = 0; ch < 3; ++ch)
                    cur[ch] = xt[ch][(r0 + q + 3) * XTW + (c + 4)];
                cur[3] = c1[q];
                cur[4] = c2[q];
                cur[5] = sigf(acc[q]);

                int pix = (R0 + r0 + q) * IMG + C0 + c;
                float* pd = out + denOff + pix * 6;        // R2-proven write pattern (frozen)
#pragma unroll
                for (int ch = 0; ch < 6; ++ch) pd[ch] = cur[ch];

                if (br == 0) {
                    float p0 = 0.0f, p1 = 0.0f;
#pragma unroll
                    for (int ch = 0; ch < 6; ++ch) {
                        p0 += wc[ch]     * cur[ch];
                        p1 += wc[6 + ch] * cur[ch];
                    }
                    pa[q][0] = p0; pa[q][1] = p1;
                } else {
                    float o0 = pa[q][0] + wc[12];
                    float o1 = pa[q][1] + wc[13];
#pragma unroll
                    for (int ch = 0; ch < 6; ++ch) {
                        o0 -= wc[ch]     * cur[ch];
                        o1 -= wc[6 + ch] * cur[ch];
                    }
                    out[pix * 2]     = o0;     // R2-proven scalar stores
                    out[pix * 2 + 1] = o1;
                }
            }
        }
    }
}

extern "C" void kernel_launch(void* const* d_in, const int* in_sizes, int n_in,
                              void* d_out, int out_size, void* d_ws, size_t ws_size,
                              hipStream_t stream) {
    const float* x   = (const float*)d_in[0];
    const float* x2  = (const float*)d_in[1];
    const float* w1a = (const float*)d_in[2];
    const float* b1a = (const float*)d_in[3];
    const float* w2a = (const float*)d_in[4];
    const float* b2a = (const float*)d_in[5];
    const float* w3a = (const float*)d_in[6];
    const float* b3a = (const float*)d_in[7];
    const float* w1b = (const float*)d_in[8];
    const float* b1b = (const float*)d_in[9];
    const float* w2b = (const float*)d_in[10];
    const float* b2b = (const float*)d_in[11];
    const float* w3b = (const float*)d_in[12];
    const float* b3b = (const float*)d_in[13];
    const float* lw1 = (const float*)d_in[14];
    const float* lb1 = (const float*)d_in[15];
    const float* lw2 = (const float*)d_in[16];
    const float* lb2 = (const float*)d_in[17];
    float* out = (float*)d_out;

    dim3 grid(IMG / TS, IMG / TS);   // 32 x 32 = 1024 blocks
    unet_fused<<<grid, 256, 0, stream>>>(x, x2,
                                         w1a, b1a, w2a, b2a, w3a, b3a,
                                         w1b, b1b, w2b, b2b, w3b, b3b,
                                         lw1, lb1, lw2, lb2, out);
}